// Round 8
// baseline (1392.473 us; speedup 1.0000x reference)
//
#include <hip/hip_runtime.h>
#include <hip/hip_bf16.h>
#include <math.h>

#define Bsz 8
#define Lq  512
#define Dm  512
#define Hh  8
#define El  4
#define DFF 2048
#define NEG (-3.0e38f)

typedef __hip_bfloat16 bf16;
typedef __attribute__((ext_vector_type(8))) short bf16x8;
typedef __attribute__((ext_vector_type(4))) float f32x4;

#define AS1 __attribute__((address_space(1)))
#define AS3 __attribute__((address_space(3)))

// ---------------- workspace layout (BYTE offsets) ----------------
#define B_H     0L            // f32 h                4096x512        8 MB
#define B_TMP   8388608L      // f32 tmp              4096x512        8 MB
#define B_SC    16777216L     // f32 scores 64x512x512 (bf16 probs in place); extras pre-attn  64 MB
#define B_HB    83886080L     // bf16 xb (512KB) + bf16 in_wT (64KB)
#define B_HPAD  88080384L     // bf16 hbp padded h    8x514x512       4.21 MB
#define B_QKV   92291072L     // bf16 qkv             4096x1536      12 MB
#define B_VT    104873984L    // bf16 vT              64x64x512       4 MB
#define B_AO    109068288L    // bf16 attn out        4096x512        4 MB
#define B_MID   113262592L    // bf16 ffn mid         4096x2048      16 MB
#define B_WC    130039808L    // bf16 conv wT         4x512x1536      6 MB
#define B_WQKV  136331264L    // bf16 qkv wT          4x1536x512      6 MB
#define B_WO    142622720L    // bf16 o wT            4x512x512       2 MB
#define B_WF1   144719872L    // bf16 f1 wT           4x2048x512      8 MB
#define B_WF2   153108480L    // bf16 f2 wT           4x512x2048      8 MB
#define B_BIAS  161497088L    // f32 qkv bias cat     4x1536         24 KB
#define B_END   161521664L

// ---------------- zero the 2 pad rows per batch in hbp ----------------
__global__ __launch_bounds__(256) void zpad(bf16* __restrict__ hbp)
{
    int i = blockIdx.x * 256 + threadIdx.x;    // 8 batches x 2 rows x 512
    if (i < 8192) {
        int b = i >> 10, r = i & 1023;
        hbp[(long)b * 263168 + r] = __float2bfloat16(0.f);
    }
}

// ---------------- embed prep: cast x->bf16, extras = in_b + ps*pos + ts*(tf@tw+tb) ----------------
__global__ __launch_bounds__(256) void prep_embed(
    const float* __restrict__ x, const float* __restrict__ tf,
    const float* __restrict__ in_b, const float* __restrict__ pos_emb,
    const float* __restrict__ temp_w, const float* __restrict__ temp_b,
    const float* __restrict__ pos_scale, const float* __restrict__ temp_scale,
    bf16* __restrict__ xb, float* __restrict__ extras)
{
    int bl = blockIdx.x, l = bl & 511, tid = threadIdx.x;
    if (tid < 64) xb[(long)bl * 64 + tid] = __float2bfloat16(x[(long)bl * 64 + tid]);
    float ps = pos_scale[0], ts = temp_scale[0];
    float t0 = tf[(long)bl * 2], t1 = tf[(long)bl * 2 + 1];
    for (int d = tid; d < 512; d += 256)
        extras[(long)bl * 512 + d] = in_b[d] + ps * pos_emb[(long)l * 512 + d]
                                   + ts * (t0 * temp_w[d] + t1 * temp_w[512 + d] + temp_b[d]);
}

// ---------------- conv weight: [dout][din][kk] -> bf16 BT[dout][kk*512+din] ----------------
__global__ __launch_bounds__(256) void convw_bf(const float* __restrict__ cw, bf16* __restrict__ out)
{
    long i = (long)blockIdx.x * 256 + threadIdx.x;
    const long total = 4L * 512 * 1536;
    if (i >= total) return;
    int din = (int)(i & 511);
    int kk  = (int)((i >> 9) % 3);
    long r  = i / 1536;
    int dout = (int)(r & 511);
    int z    = (int)(r >> 9);
    out[i] = __float2bfloat16(cw[(((long)z * 512 + dout) * 512 + din) * 3 + kk]);
}

// ---------------- generic f32 (K,N) -> bf16 (N,K) transpose, z-batched ----------------
__global__ __launch_bounds__(256) void wtrans(
    const float* __restrict__ in, bf16* __restrict__ out,
    int N, int Kd, long sIn, long sOut)
{
    int z = blockIdx.z;
    int n0 = blockIdx.x * 32, k0 = blockIdx.y * 32;
    int tid = threadIdx.x;
    int tx = tid & 31, ty = tid >> 5;   // ty 0..7
    __shared__ float t[32][33];
#pragma unroll
    for (int p = 0; p < 4; p++)
        t[ty + 8 * p][tx] = in[z * sIn + (long)(k0 + ty + 8 * p) * N + n0 + tx];
    __syncthreads();
#pragma unroll
    for (int p = 0; p < 4; p++)
        out[z * sOut + (long)(n0 + ty + 8 * p) * Kd + k0 + tx] = __float2bfloat16(t[tx][ty + 8 * p]);
}

// ---------------- concat q/k/v biases ----------------
__global__ __launch_bounds__(256) void biascat(
    const float* __restrict__ qb, const float* __restrict__ kb,
    const float* __restrict__ vb, float* __restrict__ out)
{
    int i = blockIdx.x * 256 + threadIdx.x;
    if (i >= 4 * 1536) return;
    int l = i / 1536, j = i - l * 1536;
    float v = (j < 512) ? qb[l * 512 + j] : (j < 1024) ? kb[l * 512 + j - 512] : vb[l * 512 + j - 1024];
    out[i] = v;
}

// ---------------- residual + LayerNorm -> f32 h + bf16 copy into padded hbp ----------------
__global__ __launch_bounds__(256) void ln_kernel(
    float* __restrict__ h, bf16* __restrict__ hbp, const float* __restrict__ r,
    const float* __restrict__ sc, const float* __restrict__ bi)
{
    long base = (long)blockIdx.x * Dm;
    int b = blockIdx.x >> 9;
    long hbase = base + (long)(b + 1) * 1024;   // hbp row = bl + 2*b + 2
    int tid = threadIdx.x;
    float v0 = h[base + tid] + r[base + tid];
    float v1 = h[base + tid + 256] + r[base + tid + 256];
    __shared__ float red[16];
    int lane = tid & 63, wid = tid >> 6;
    float s = v0 + v1;
    for (int off = 32; off; off >>= 1) s += __shfl_down(s, off);
    if (!lane) red[wid] = s;
    __syncthreads();
    float mean = (red[0] + red[1] + red[2] + red[3]) * (1.f / 512.f);
    float d0 = v0 - mean, d1 = v1 - mean;
    float vs = d0 * d0 + d1 * d1;
    for (int off = 32; off; off >>= 1) vs += __shfl_down(vs, off);
    if (!lane) red[4 + wid] = vs;
    __syncthreads();
    float var = (red[4] + red[5] + red[6] + red[7]) * (1.f / 512.f);
    float inv = rsqrtf(var + 1e-5f);
    float o0 = d0 * inv * sc[tid] + bi[tid];
    float o1 = d1 * inv * sc[tid + 256] + bi[tid + 256];
    h[base + tid]         = o0;
    h[base + tid + 256]   = o1;
    hbp[hbase + tid]       = __float2bfloat16(o0);
    hbp[hbase + tid + 256] = __float2bfloat16(o1);
}

// ---------------- v transpose: qkv v-part [pos][d] -> vT [z][d][pos] bf16 ----------------
__global__ __launch_bounds__(256) void vtrans(const bf16* __restrict__ qkv, bf16* __restrict__ vT)
{
    int z = blockIdx.y, b = z >> 3, hh = z & 7;
    int pos0 = blockIdx.x * 64;
    __shared__ bf16 T[64][65];
    int tid = threadIdx.x;
    int d = tid & 63, pr = tid >> 6;
    const bf16* src = qkv + ((long)(b * 512 + pos0)) * 1536 + 1024 + hh * 64;
#pragma unroll
    for (int p = 0; p < 16; p++)
        T[pr + 4 * p][d] = src[(long)(pr + 4 * p) * 1536 + d];
    __syncthreads();
    bf16* dst = vT + (long)z * 32768 + pos0;
    int c = tid & 63, dr = tid >> 6;
#pragma unroll
    for (int p = 0; p < 16; p++)
        dst[(long)(dr + 4 * p) * 512 + c] = T[c][dr + 4 * p];
}

// ---------------- MFMA bf16 GEMM: one wave / 64x64 tile, 4-stage LDS pipeline, no barriers -------
// A: [M][K] bf16 (lda), B: [N][K] bf16 (ldb). z: zb=z/zdiv, zr=z%zdiv.
// flags: 1 = skip tiles with bx>by (triangular), 2 = Kend = min(K, m0+64) (causal A).
// XCD swizzle: bx=id/gridDim.y, by=id%gridDim.y groups same-A blocks on one XCD (ids = by mod 8).
// Pipeline: 3 stages in flight; steady-state wait vmcnt(24) = stage issued 3 iters ago.
__global__ __launch_bounds__(64) void mm_bt(
    const bf16* __restrict__ A, int lda, long sAo, long sAi,
    const bf16* __restrict__ B, int ldb, long sBo, long sBi,
    float* __restrict__ Cf, bf16* __restrict__ Cb, int ldc, long sCo, long sCi,
    int K, int zdiv, int Nvalid, int flags,
    const float* __restrict__ bias, const float* __restrict__ Res,
    bf16* __restrict__ C2, int relu, float scale)
{
    int id = blockIdx.x + gridDim.x * blockIdx.y;
    int bx = id / gridDim.y;
    int by = id - bx * gridDim.y;
    if ((flags & 1) && bx > by) return;
    int z = blockIdx.z;
    int zb = z / zdiv, zr = z - zb * zdiv;
    const bf16* Ap = A + zb * sAo + zr * sAi;
    const bf16* Bp = B + zb * sBo + zr * sBi;
    long cbase = zb * sCo + zr * sCi;
    int m0 = by * 64, n0 = bx * 64;
    __shared__ __align__(16) bf16 As[4][2048];   // four 64x32 panels
    __shared__ __align__(16) bf16 Bs[4][2048];
    int lane = threadIdx.x;
    int lr = lane >> 2, lc = (lane & 3) * 8;     // staging: 4 lanes cover 64B of one row
    int fm = lane & 15, fq = lane >> 4;
    const bf16* gA[4]; const bf16* gB[4];
#pragma unroll
    for (int p = 0; p < 4; p++) {
        gA[p] = Ap + (long)(m0 + p * 16 + lr) * lda + lc;
        gB[p] = Bp + (long)(n0 + p * 16 + lr) * ldb + lc;
    }
    int Kend = (flags & 2) ? ((K < m0 + 64) ? K : (m0 + 64)) : K;
    int nIter = Kend >> 5;
    f32x4 acc[4][4] = {};
    // preload stages 0..2
#pragma unroll
    for (int s = 0; s < 3; s++) {
        if (s < nIter) {
            int k = s << 5;
#pragma unroll
            for (int p = 0; p < 4; p++) {
                __builtin_amdgcn_global_load_lds((const AS1 void*)(gA[p] + k), (AS3 void*)(&As[s][p * 512]), 16, 0, 0);
                __builtin_amdgcn_global_load_lds((const AS1 void*)(gB[p] + k), (AS3 void*)(&Bs[s][p * 512]), 16, 0, 0);
            }
        }
    }
    for (int it = 0; it < nIter; ++it) {
        int cur = it & 3;
        if (it + 3 < nIter) {
            int nk = (it + 3) << 5;
            int nb = (it + 3) & 3;
#pragma unroll
            for (int p = 0; p < 4; p++) {
                __builtin_amdgcn_global_load_lds((const AS1 void*)(gA[p] + nk), (AS3 void*)(&As[nb][p * 512]), 16, 0, 0);
                __builtin_amdgcn_global_load_lds((const AS1 void*)(gB[p] + nk), (AS3 void*)(&Bs[nb][p * 512]), 16, 0, 0);
            }
        }
        int rem = nIter - 1 - it; if (rem > 3) rem = 3;   // stages allowed to stay in flight
        if (rem == 3)      __asm__ __volatile__("s_waitcnt vmcnt(24)" ::: "memory");
        else if (rem == 2) __asm__ __volatile__("s_waitcnt vmcnt(16)" ::: "memory");
        else if (rem == 1) __asm__ __volatile__("s_waitcnt vmcnt(8)"  ::: "memory");
        else               __asm__ __volatile__("s_waitcnt vmcnt(0)"  ::: "memory");
        bf16x8 af[4], bfr[4];
#pragma unroll
        for (int t = 0; t < 4; t++) {
            af[t]  = *(const bf16x8*)(&As[cur][(t * 16 + fm) * 32 + fq * 8]);
            bfr[t] = *(const bf16x8*)(&Bs[cur][(t * 16 + fm) * 32 + fq * 8]);
        }
#pragma unroll
        for (int i = 0; i < 4; i++)
#pragma unroll
            for (int j = 0; j < 4; j++)
                acc[i][j] = __builtin_amdgcn_mfma_f32_16x16x32_bf16(af[i], bfr[j], acc[i][j], 0, 0, 0);
    }

#pragma unroll
    for (int i = 0; i < 4; i++) {
        int mrow = m0 + i * 16 + fq * 4;
#pragma unroll
        for (int j = 0; j < 4; j++) {
            int n = n0 + j * 16 + fm;
            if (n < Nvalid) {
                float bs = bias ? bias[n] : 0.f;
#pragma unroll
                for (int r = 0; r < 4; r++) {
                    float c = acc[i][j][r] * scale + bs;
                    if (relu) c = fmaxf(c, 0.f);
                    long addr = cbase + (long)(mrow + r) * ldc + n;
                    if (Res) c += Res[addr];
                    if (Cf) Cf[addr] = c;
                    else    Cb[addr] = __float2bfloat16(c);
                    if (C2) C2[addr + (long)(((mrow + r) >> 9) + 1) * 1024] = __float2bfloat16(c);
                }
            }
        }
    }
}

// ---------------- top-k(256) threshold (exact radix select) + softmax; one wave per row ----------
__global__ __launch_bounds__(256) void topk_softmax(float* __restrict__ sc)
{
    int wave = threadIdx.x >> 6, lane = threadIdx.x & 63;
    int row = blockIdx.x * 4 + wave;   // z*512 + q
    int q = row & 511, z = row >> 9;
    float* s = sc + (long)z * 262144 + (long)q * 512;
    __shared__ int hist[4][256];
    int* H = hist[wave];
    float v[8]; unsigned key[8]; bool val[8];
#pragma unroll
    for (int p = 0; p < 8; p++) {
        int c = lane + 64 * p;
        val[p] = (c <= q);
        v[p] = val[p] ? s[c] : NEG;
        unsigned u = __float_as_uint(v[p]);
        key[p] = u ^ (unsigned)(((int)u >> 31) | 0x80000000);
    }
    unsigned prefix = 0u, pmask = 0u; int kneed = 256;
#pragma unroll
    for (int shift = 24; shift >= 0; shift -= 8) {
#pragma unroll
        for (int i = 0; i < 4; i++) H[lane * 4 + i] = 0;
        __syncthreads();
#pragma unroll
        for (int p = 0; p < 8; p++)
            if (val[p] && (key[p] & pmask) == prefix)
                atomicAdd(&H[(key[p] >> shift) & 255], 1);
        __syncthreads();
        int b4 = lane * 4;
        int s0 = H[b4], s1 = H[b4 + 1], s2 = H[b4 + 2], s3 = H[b4 + 3];
        int tot = s0 + s1 + s2 + s3, run = tot;
#pragma unroll
        for (int off = 1; off < 64; off <<= 1) {
            int o = __shfl_down(run, off);
            if (lane + off < 64) run += o;
        }
        int above = run - tot;
        unsigned pack = 0u;
        if (above < kneed && kneed <= above + tot) {
            int c3 = above + s3, c2 = c3 + s2, c1 = c2 + s1;
            int dsel, rem;
            if (kneed <= c3)      { dsel = 3; rem = kneed - above; }
            else if (kneed <= c2) { dsel = 2; rem = kneed - c3; }
            else if (kneed <= c1) { dsel = 1; rem = kneed - c2; }
            else                  { dsel = 0; rem = kneed - c1; }
            pack = ((unsigned)(b4 + dsel) << 10) | (unsigned)rem;
        }
#pragma unroll
        for (int off = 1; off < 64; off <<= 1) pack |= __shfl_xor(pack, off);
        prefix |= (pack >> 10) << shift;
        kneed = (int)(pack & 1023u);
        pmask |= (0xFFu << shift);
        __syncthreads();
    }
    unsigned Tkey = prefix;
    float m = NEG;
#pragma unroll
    for (int p = 0; p < 8; p++) m = fmaxf(m, v[p]);
#pragma unroll
    for (int off = 1; off < 64; off <<= 1) m = fmaxf(m, __shfl_xor(m, off));
    float e[8]; float ssum = 0.f;
#pragma unroll
    for (int p = 0; p < 8; p++) {
        bool kp = val[p] && (key[p] >= Tkey);
        e[p] = kp ? expf(v[p] - m) : 0.f;
        ssum += e[p];
    }
#pragma unroll
    for (int off = 1; off < 64; off <<= 1) ssum += __shfl_xor(ssum, off);
    float inv = 1.f / ssum;
    bf16* sb = (bf16*)s;                  // in-place bf16 probs, row stride 1024 bf16
#pragma unroll
    for (int p = 0; p < 8; p++) sb[lane + 64 * p] = __float2bfloat16(e[p] * inv);
}

extern "C" void kernel_launch(void* const* d_in, const int* in_sizes, int n_in,
                              void* d_out, int out_size, void* d_ws, size_t ws_size,
                              hipStream_t stream)
{
    const float* x         = (const float*)d_in[0];
    const float* tf        = (const float*)d_in[1];
    const float* in_w      = (const float*)d_in[2];
    const float* in_b      = (const float*)d_in[3];
    const float* pos_emb   = (const float*)d_in[4];
    const float* temp_w    = (const float*)d_in[5];
    const float* temp_b    = (const float*)d_in[6];
    const float* pos_scale = (const float*)d_in[7];
    const float* temp_scale= (const float*)d_in[8];
    const float* conv_w    = (const float*)d_in[9];
    const float* conv_b    = (const float*)d_in[10];
    const float* qw        = (const float*)d_in[11];
    const float* qb        = (const float*)d_in[12];
    const float* kw        = (const float*)d_in[13];
    const float* kb        = (const float*)d_in[14];
    const float* vw        = (const float*)d_in[15];
    const float* vb        = (const float*)d_in[16];
    const float* ow        = (const float*)d_in[17];
    const float* ob        = (const float*)d_in[18];
    const float* f1w       = (const float*)d_in[19];
    const float* f1b       = (const float*)d_in[20];
    const float* f2w       = (const float*)d_in[21];
    const float* f2b       = (const float*)d_in[22];
    const float* n1s       = (const float*)d_in[23];
    const float* n1b       = (const float*)d_in[24];
    const float* n2s       = (const float*)d_in[25];
    const float* n2b       = (const float*)d_in[26];

    if (ws_size < (size_t)B_END) return;

    char* wsb = (char*)d_ws;
    float* h    = (float*)(wsb + B_H);
    float* tmp  = (float*)(wsb + B_TMP);
    float* scb  = (float*)(wsb + B_SC);
    float* extras = (float*)(wsb + B_SC);          // reuses scores region before attention
    bf16*  xb   = (bf16*)(wsb + B_HB);
    bf16*  inwT = (bf16*)(wsb + B_HB + 1048576);
    bf16*  hbp  = (bf16*)(wsb + B_HPAD);           // [8][514][512] padded bf16 h
    bf16*  qkv  = (bf16*)(wsb + B_QKV);
    bf16*  vT   = (bf16*)(wsb + B_VT);
    bf16*  ao   = (bf16*)(wsb + B_AO);
    bf16*  mid  = (bf16*)(wsb + B_MID);
    bf16*  wC   = (bf16*)(wsb + B_WC);
    bf16*  wQKV = (bf16*)(wsb + B_WQKV);
    bf16*  wO   = (bf16*)(wsb + B_WO);
    bf16*  wF1  = (bf16*)(wsb + B_WF1);
    bf16*  wF2  = (bf16*)(wsb + B_WF2);
    float* bqkv = (float*)(wsb + B_BIAS);

    // ---- weight prep ----
    convw_bf<<<(4 * 512 * 1536) / 256, 256, 0, stream>>>(conv_w, wC);
    {
        dim3 gw(16, 2, 1);
        wtrans<<<gw, 256, 0, stream>>>(in_w, inwT,         512, 64, 0L, 0L);
        dim3 g(16, 16, 4);
        wtrans<<<g, 256, 0, stream>>>(qw, wQKV,            512, 512, 262144L, 786432L);
        wtrans<<<g, 256, 0, stream>>>(kw, wQKV + 262144,   512, 512, 262144L, 786432L);
        wtrans<<<g, 256, 0, stream>>>(vw, wQKV + 524288,   512, 512, 262144L, 786432L);
        wtrans<<<g, 256, 0, stream>>>(ow, wO,              512, 512, 262144L, 262144L);
        dim3 g1(64, 16, 4);
        wtrans<<<g1, 256, 0, stream>>>(f1w, wF1,          2048, 512, 1048576L, 1048576L);
        dim3 g2(16, 64, 4);
        wtrans<<<g2, 256, 0, stream>>>(f2w, wF2,           512, 2048, 1048576L, 1048576L);
    }
    biascat<<<24, 256, 0, stream>>>(qb, kb, vb, bqkv);
    zpad<<<32, 256, 0, stream>>>(hbp);
    prep_embed<<<4096, 256, 0, stream>>>(x, tf, in_b, pos_emb, temp_w, temp_b,
                                         pos_scale, temp_scale, xb, extras);
    // embed = x @ in_w + extras  -> h (f32) + hbp (bf16, padded)
    {
        dim3 g(8, 64, 1);
        mm_bt<<<g, 64, 0, stream>>>(xb, 64, 0L, 0L,
                                    inwT, 64, 0L, 0L,
                                    h, nullptr, 512, 0L, 0L,
                                    64, 1, 512, 0,
                                    nullptr, extras, hbp, 0, 1.f);
    }

    for (int l = 0; l < El; l++) {
        // causal conv as GEMM over padded hbp window, K = 3*512, z-batched
        {
            dim3 g(8, 8, 8);
            mm_bt<<<g, 64, 0, stream>>>(hbp, 512, 263168L, 0L,
                                        wC + (long)l * 786432, 1536, 0L, 0L,
                                        tmp, nullptr, 512, 262144L, 0L,
                                        1536, 1, 512, 0,
                                        conv_b + (long)l * 512, nullptr, nullptr, 0, 1.f);
        }
        ln_kernel<<<Bsz * Lq, 256, 0, stream>>>(h, hbp, tmp, n1s + (long)l * 512, n1b + (long)l * 512);

        // fused QKV (z-batched over batch): [512,512] @ [512,1536] per b
        {
            dim3 g(24, 8, 8);
            mm_bt<<<g, 64, 0, stream>>>(hbp + 1024, 512, 263168L, 0L,
                                        wQKV + (long)l * 786432, 512, 0L, 0L,
                                        nullptr, qkv, 1536, 786432L, 0L,
                                        512, 1, 1536, 0,
                                        bqkv + (long)l * 1536, nullptr, nullptr, 0, 1.f);
        }

        // scores = 0.125 * q @ k^T (lower-triangle tiles) -> f32 scb
        {
            dim3 g(8, 8, 64);
            mm_bt<<<g, 64, 0, stream>>>(qkv, 1536, 786432L, 64L,
                                        qkv + 512, 1536, 786432L, 64L,
                                        scb, nullptr, 512, 2097152L, 262144L,
                                        64, 8, 512, 1,
                                        nullptr, nullptr, nullptr, 0, 0.125f);
        }
        topk_softmax<<<Bsz * Hh * Lq / 4, 256, 0, stream>>>(scb);
        {
            dim3 gv(8, 64, 1);
            vtrans<<<gv, 256, 0, stream>>>(qkv, vT);
        }
        // attn @ v : causal K limit, Nvalid=64
        {
            dim3 g(1, 8, 64);
            mm_bt<<<g, 64, 0, stream>>>((const bf16*)scb, 1024, 4194304L, 524288L,
                                        vT, 512, 262144L, 32768L,
                                        nullptr, ao, 512, 262144L, 64L,
                                        512, 8, 64, 2,
                                        nullptr, nullptr, nullptr, 0, 1.f);
        }
        // out proj
        {
            dim3 g(8, 64, 1);
            mm_bt<<<g, 64, 0, stream>>>(ao, 512, 0L, 0L,
                                        wO + (long)l * 262144, 512, 0L, 0L,
                                        tmp, nullptr, 512, 0L, 0L,
                                        512, 1, 512, 0,
                                        ob + (long)l * 512, nullptr, nullptr, 0, 1.f);
        }
        ln_kernel<<<Bsz * Lq, 256, 0, stream>>>(h, hbp, tmp, n2s + (long)l * 512, n2b + (long)l * 512);

        // FFN1 (relu) -> bf16 mid, z-batched
        {
            dim3 g(32, 8, 8);
            mm_bt<<<g, 64, 0, stream>>>(hbp + 1024, 512, 263168L, 0L,
                                        wF1 + (long)l * 1048576, 512, 0L, 0L,
                                        nullptr, mid, 2048, 1048576L, 0L,
                                        512, 1, 2048, 0,
                                        f1b + (long)l * 2048, nullptr, nullptr, 1, 1.f);
        }
        // FFN2 + residual -> f32 h + bf16 hbp (padded)
        {
            dim3 g(8, 64, 1);
            mm_bt<<<g, 64, 0, stream>>>(mid, 2048, 0L, 0L,
                                        wF2 + (long)l * 1048576, 2048, 0L, 0L,
                                        h, nullptr, 512, 0L, 0L,
                                        2048, 1, 512, 0,
                                        f2b + (long)l * 512, h, hbp, 0, 1.f);
        }
    }

    hipMemcpyAsync(d_out, h, (size_t)out_size * sizeof(float), hipMemcpyDeviceToDevice, stream);
}

// Round 9
// 1167.729 us; speedup vs baseline: 1.1925x; 1.1925x over previous
//
#include <hip/hip_runtime.h>
#include <hip/hip_bf16.h>
#include <math.h>

#define Bsz 8
#define Lq  512
#define Dm  512
#define Hh  8
#define El  4
#define DFF 2048
#define NEG (-3.0e38f)

typedef __hip_bfloat16 bf16;
typedef __attribute__((ext_vector_type(8))) short bf16x8;
typedef __attribute__((ext_vector_type(4))) float f32x4;

#define AS1 __attribute__((address_space(1)))
#define AS3 __attribute__((address_space(3)))

// ---------------- workspace layout (BYTE offsets) ----------------
#define B_H     0L            // f32 h                4096x512        8 MB
#define B_TMP   8388608L      // f32 tmp              4096x512        8 MB
#define B_SC    16777216L     // f32 scores 64x512x512 (bf16 probs in place); extras pre-attn  64 MB
#define B_HB    83886080L     // bf16 xb (512KB) + bf16 in_wT (64KB)
#define B_HPAD  88080384L     // bf16 hbp padded h    8x514x512       4.21 MB
#define B_QKV   92291072L     // bf16 qkv             4096x1536      12 MB
#define B_VT    104873984L    // bf16 vT              64x64x512       4 MB
#define B_AO    109068288L    // bf16 attn out        4096x512        4 MB
#define B_MID   113262592L    // bf16 ffn mid         4096x2048      16 MB
#define B_WC    130039808L    // bf16 conv wT         4x512x1536      6 MB
#define B_WQKV  136331264L    // bf16 qkv wT          4x1536x512      6 MB
#define B_WO    142622720L    // bf16 o wT            4x512x512       2 MB
#define B_WF1   144719872L    // bf16 f1 wT           4x2048x512      8 MB
#define B_WF2   153108480L    // bf16 f2 wT           4x512x2048      8 MB
#define B_BIAS  161497088L    // f32 qkv bias cat     4x1536         24 KB
#define B_END   161521664L

// ---------------- zero the 2 pad rows per batch in hbp ----------------
__global__ __launch_bounds__(256) void zpad(bf16* __restrict__ hbp)
{
    int i = blockIdx.x * 256 + threadIdx.x;    // 8 batches x 2 rows x 512
    if (i < 8192) {
        int b = i >> 10, r = i & 1023;
        hbp[(long)b * 263168 + r] = __float2bfloat16(0.f);
    }
}

// ---------------- embed prep: cast x->bf16, extras = in_b + ps*pos + ts*(tf@tw+tb) ----------------
__global__ __launch_bounds__(256) void prep_embed(
    const float* __restrict__ x, const float* __restrict__ tf,
    const float* __restrict__ in_b, const float* __restrict__ pos_emb,
    const float* __restrict__ temp_w, const float* __restrict__ temp_b,
    const float* __restrict__ pos_scale, const float* __restrict__ temp_scale,
    bf16* __restrict__ xb, float* __restrict__ extras)
{
    int bl = blockIdx.x, l = bl & 511, tid = threadIdx.x;
    if (tid < 64) xb[(long)bl * 64 + tid] = __float2bfloat16(x[(long)bl * 64 + tid]);
    float ps = pos_scale[0], ts = temp_scale[0];
    float t0 = tf[(long)bl * 2], t1 = tf[(long)bl * 2 + 1];
    for (int d = tid; d < 512; d += 256)
        extras[(long)bl * 512 + d] = in_b[d] + ps * pos_emb[(long)l * 512 + d]
                                   + ts * (t0 * temp_w[d] + t1 * temp_w[512 + d] + temp_b[d]);
}

// ---------------- conv weight: [dout][din][kk] -> bf16 BT[dout][kk*512+din] ----------------
__global__ __launch_bounds__(256) void convw_bf(const float* __restrict__ cw, bf16* __restrict__ out)
{
    long i = (long)blockIdx.x * 256 + threadIdx.x;
    const long total = 4L * 512 * 1536;
    if (i >= total) return;
    int din = (int)(i & 511);
    int kk  = (int)((i >> 9) % 3);
    long r  = i / 1536;
    int dout = (int)(r & 511);
    int z    = (int)(r >> 9);
    out[i] = __float2bfloat16(cw[(((long)z * 512 + dout) * 512 + din) * 3 + kk]);
}

// ---------------- generic f32 (K,N) -> bf16 (N,K) transpose, z-batched ----------------
__global__ __launch_bounds__(256) void wtrans(
    const float* __restrict__ in, bf16* __restrict__ out,
    int N, int Kd, long sIn, long sOut)
{
    int z = blockIdx.z;
    int n0 = blockIdx.x * 32, k0 = blockIdx.y * 32;
    int tid = threadIdx.x;
    int tx = tid & 31, ty = tid >> 5;   // ty 0..7
    __shared__ float t[32][33];
#pragma unroll
    for (int p = 0; p < 4; p++)
        t[ty + 8 * p][tx] = in[z * sIn + (long)(k0 + ty + 8 * p) * N + n0 + tx];
    __syncthreads();
#pragma unroll
    for (int p = 0; p < 4; p++)
        out[z * sOut + (long)(n0 + ty + 8 * p) * Kd + k0 + tx] = __float2bfloat16(t[tx][ty + 8 * p]);
}

// ---------------- concat q/k/v biases ----------------
__global__ __launch_bounds__(256) void biascat(
    const float* __restrict__ qb, const float* __restrict__ kb,
    const float* __restrict__ vb, float* __restrict__ out)
{
    int i = blockIdx.x * 256 + threadIdx.x;
    if (i >= 4 * 1536) return;
    int l = i / 1536, j = i - l * 1536;
    float v = (j < 512) ? qb[l * 512 + j] : (j < 1024) ? kb[l * 512 + j - 512] : vb[l * 512 + j - 1024];
    out[i] = v;
}

// ---------------- residual + LayerNorm -> f32 h + bf16 copy into padded hbp ----------------
__global__ __launch_bounds__(256) void ln_kernel(
    float* __restrict__ h, bf16* __restrict__ hbp, const float* __restrict__ r,
    const float* __restrict__ sc, const float* __restrict__ bi)
{
    long base = (long)blockIdx.x * Dm;
    int b = blockIdx.x >> 9;
    long hbase = base + (long)(b + 1) * 1024;   // hbp row = bl + 2*b + 2
    int tid = threadIdx.x;
    float v0 = h[base + tid] + r[base + tid];
    float v1 = h[base + tid + 256] + r[base + tid + 256];
    __shared__ float red[16];
    int lane = tid & 63, wid = tid >> 6;
    float s = v0 + v1;
    for (int off = 32; off; off >>= 1) s += __shfl_down(s, off);
    if (!lane) red[wid] = s;
    __syncthreads();
    float mean = (red[0] + red[1] + red[2] + red[3]) * (1.f / 512.f);
    float d0 = v0 - mean, d1 = v1 - mean;
    float vs = d0 * d0 + d1 * d1;
    for (int off = 32; off; off >>= 1) vs += __shfl_down(vs, off);
    if (!lane) red[4 + wid] = vs;
    __syncthreads();
    float var = (red[4] + red[5] + red[6] + red[7]) * (1.f / 512.f);
    float inv = rsqrtf(var + 1e-5f);
    float o0 = d0 * inv * sc[tid] + bi[tid];
    float o1 = d1 * inv * sc[tid + 256] + bi[tid + 256];
    h[base + tid]         = o0;
    h[base + tid + 256]   = o1;
    hbp[hbase + tid]       = __float2bfloat16(o0);
    hbp[hbase + tid + 256] = __float2bfloat16(o1);
}

// ---------------- v transpose: qkv v-part [pos][d] -> vT [z][d][pos] bf16 ----------------
__global__ __launch_bounds__(256) void vtrans(const bf16* __restrict__ qkv, bf16* __restrict__ vT)
{
    int z = blockIdx.y, b = z >> 3, hh = z & 7;
    int pos0 = blockIdx.x * 64;
    __shared__ bf16 T[64][65];
    int tid = threadIdx.x;
    int d = tid & 63, pr = tid >> 6;
    const bf16* src = qkv + ((long)(b * 512 + pos0)) * 1536 + 1024 + hh * 64;
#pragma unroll
    for (int p = 0; p < 16; p++)
        T[pr + 4 * p][d] = src[(long)(pr + 4 * p) * 1536 + d];
    __syncthreads();
    bf16* dst = vT + (long)z * 32768 + pos0;
    int c = tid & 63, dr = tid >> 6;
#pragma unroll
    for (int p = 0; p < 16; p++)
        dst[(long)(dr + 4 * p) * 512 + c] = T[c][dr + 4 * p];
}

// ---------------- MFMA bf16 GEMM: one wave / TMx64 tile, 3-stage LDS pipeline, no barriers -------
// A: [M][K] bf16 (lda), B: [N][K] bf16 (ldb). z: zb=z/zdiv, zr=z%zdiv.
// flags: 1 = skip tiles fully above diagonal (n0 > m0+TM-1), 2 = Kend = min(K, m0+TM) (causal A;
//        prob cols beyond causal range are exactly 0, so rounding up to 32 is safe).
// XCD swizzle: bx=id/gridDim.y, by=id%gridDim.y -> same-A blocks share id%8 (gridDim.y % 8 == 0).
template<int TM>
__global__ __launch_bounds__(64) void mm_bt(
    const bf16* __restrict__ A, int lda, long sAo, long sAi,
    const bf16* __restrict__ B, int ldb, long sBo, long sBi,
    float* __restrict__ Cf, bf16* __restrict__ Cb, int ldc, long sCo, long sCi,
    int K, int zdiv, int Nvalid, int flags,
    const float* __restrict__ bias, const float* __restrict__ Res,
    bf16* __restrict__ C2, int relu, float scale)
{
    constexpr int LA = TM / 16;          // A staging loads per stage
    int id = blockIdx.x + gridDim.x * blockIdx.y;
    int bx = id / gridDim.y;
    int by = id - bx * gridDim.y;
    int m0 = by * TM, n0 = bx * 64;
    if ((flags & 1) && n0 > m0 + TM - 1) return;
    int z = blockIdx.z;
    int zb = z / zdiv, zr = z - zb * zdiv;
    const bf16* Ap = A + zb * sAo + zr * sAi;
    const bf16* Bp = B + zb * sBo + zr * sBi;
    long cbase = zb * sCo + zr * sCi;
    __shared__ __align__(16) bf16 As[3][TM * 32];
    __shared__ __align__(16) bf16 Bs[3][64 * 32];
    int lane = threadIdx.x;
    int lr = lane >> 2, lc = (lane & 3) * 8;     // staging: 4 lanes cover 64B of one row
    int fm = lane & 15, fq = lane >> 4;
    const bf16* gA[LA]; const bf16* gB[4];
#pragma unroll
    for (int p = 0; p < LA; p++) gA[p] = Ap + (long)(m0 + p * 16 + lr) * lda + lc;
#pragma unroll
    for (int p = 0; p < 4; p++)  gB[p] = Bp + (long)(n0 + p * 16 + lr) * ldb + lc;
    int Kend = (flags & 2) ? ((K < m0 + TM) ? K : (m0 + TM)) : K;
    int nIter = (Kend + 31) >> 5;
    f32x4 acc[LA][4] = {};
    // preload stages 0,1
#pragma unroll
    for (int s = 0; s < 2; s++) {
        if (s < nIter) {
            int k = s << 5;
#pragma unroll
            for (int p = 0; p < LA; p++)
                __builtin_amdgcn_global_load_lds((const AS1 void*)(gA[p] + k), (AS3 void*)(&As[s][p * 512]), 16, 0, 0);
#pragma unroll
            for (int p = 0; p < 4; p++)
                __builtin_amdgcn_global_load_lds((const AS1 void*)(gB[p] + k), (AS3 void*)(&Bs[s][p * 512]), 16, 0, 0);
        }
    }
    int cur = 0, nxt = 2;
    for (int it = 0; it < nIter; ++it) {
        if (it + 2 < nIter) {
            int nk = (it + 2) << 5;
#pragma unroll
            for (int p = 0; p < LA; p++)
                __builtin_amdgcn_global_load_lds((const AS1 void*)(gA[p] + nk), (AS3 void*)(&As[nxt][p * 512]), 16, 0, 0);
#pragma unroll
            for (int p = 0; p < 4; p++)
                __builtin_amdgcn_global_load_lds((const AS1 void*)(gB[p] + nk), (AS3 void*)(&Bs[nxt][p * 512]), 16, 0, 0);
        }
        int rem = nIter - 1 - it; if (rem > 2) rem = 2;
        if (rem == 2) {
            if constexpr (TM == 32) __asm__ __volatile__("s_waitcnt vmcnt(12)" ::: "memory");
            else                    __asm__ __volatile__("s_waitcnt vmcnt(10)" ::: "memory");
        } else if (rem == 1) {
            if constexpr (TM == 32) __asm__ __volatile__("s_waitcnt vmcnt(6)" ::: "memory");
            else                    __asm__ __volatile__("s_waitcnt vmcnt(5)" ::: "memory");
        } else {
            __asm__ __volatile__("s_waitcnt vmcnt(0)" ::: "memory");
        }
        bf16x8 af[LA], bfr[4];
#pragma unroll
        for (int t = 0; t < LA; t++) af[t] = *(const bf16x8*)(&As[cur][(t * 16 + fm) * 32 + fq * 8]);
#pragma unroll
        for (int t = 0; t < 4; t++) bfr[t] = *(const bf16x8*)(&Bs[cur][(t * 16 + fm) * 32 + fq * 8]);
#pragma unroll
        for (int i = 0; i < LA; i++)
#pragma unroll
            for (int j = 0; j < 4; j++)
                acc[i][j] = __builtin_amdgcn_mfma_f32_16x16x32_bf16(af[i], bfr[j], acc[i][j], 0, 0, 0);
        cur = (cur == 2) ? 0 : cur + 1;
        nxt = (nxt == 2) ? 0 : nxt + 1;
    }

#pragma unroll
    for (int i = 0; i < LA; i++) {
        int mrow = m0 + i * 16 + fq * 4;
#pragma unroll
        for (int j = 0; j < 4; j++) {
            int n = n0 + j * 16 + fm;
            if (n < Nvalid) {
                float bs = bias ? bias[n] : 0.f;
#pragma unroll
                for (int r = 0; r < 4; r++) {
                    float c = acc[i][j][r] * scale + bs;
                    if (relu) c = fmaxf(c, 0.f);
                    long addr = cbase + (long)(mrow + r) * ldc + n;
                    if (Res) c += Res[addr];
                    if (Cf) Cf[addr] = c;
                    else    Cb[addr] = __float2bfloat16(c);
                    if (C2) C2[addr + (long)(((mrow + r) >> 9) + 1) * 1024] = __float2bfloat16(c);
                }
            }
        }
    }
}

// ---------------- top-k(256) threshold (exact radix select) + softmax; one wave per row ----------
__global__ __launch_bounds__(256) void topk_softmax(float* __restrict__ sc)
{
    int wave = threadIdx.x >> 6, lane = threadIdx.x & 63;
    int row = blockIdx.x * 4 + wave;   // z*512 + q
    int q = row & 511, z = row >> 9;
    float* s = sc + (long)z * 262144 + (long)q * 512;
    __shared__ int hist[4][256];
    int* H = hist[wave];
    float v[8]; unsigned key[8]; bool val[8];
#pragma unroll
    for (int p = 0; p < 8; p++) {
        int c = lane + 64 * p;
        val[p] = (c <= q);
        v[p] = val[p] ? s[c] : NEG;
        unsigned u = __float_as_uint(v[p]);
        key[p] = u ^ (unsigned)(((int)u >> 31) | 0x80000000);
    }
    unsigned prefix = 0u, pmask = 0u; int kneed = 256;
#pragma unroll
    for (int shift = 24; shift >= 0; shift -= 8) {
#pragma unroll
        for (int i = 0; i < 4; i++) H[lane * 4 + i] = 0;
        __syncthreads();
#pragma unroll
        for (int p = 0; p < 8; p++)
            if (val[p] && (key[p] & pmask) == prefix)
                atomicAdd(&H[(key[p] >> shift) & 255], 1);
        __syncthreads();
        int b4 = lane * 4;
        int s0 = H[b4], s1 = H[b4 + 1], s2 = H[b4 + 2], s3 = H[b4 + 3];
        int tot = s0 + s1 + s2 + s3, run = tot;
#pragma unroll
        for (int off = 1; off < 64; off <<= 1) {
            int o = __shfl_down(run, off);
            if (lane + off < 64) run += o;
        }
        int above = run - tot;
        unsigned pack = 0u;
        if (above < kneed && kneed <= above + tot) {
            int c3 = above + s3, c2 = c3 + s2, c1 = c2 + s1;
            int dsel, rem;
            if (kneed <= c3)      { dsel = 3; rem = kneed - above; }
            else if (kneed <= c2) { dsel = 2; rem = kneed - c3; }
            else if (kneed <= c1) { dsel = 1; rem = kneed - c2; }
            else                  { dsel = 0; rem = kneed - c1; }
            pack = ((unsigned)(b4 + dsel) << 10) | (unsigned)rem;
        }
#pragma unroll
        for (int off = 1; off < 64; off <<= 1) pack |= __shfl_xor(pack, off);
        prefix |= (pack >> 10) << shift;
        kneed = (int)(pack & 1023u);
        pmask |= (0xFFu << shift);
        __syncthreads();
    }
    unsigned Tkey = prefix;
    float m = NEG;
#pragma unroll
    for (int p = 0; p < 8; p++) m = fmaxf(m, v[p]);
#pragma unroll
    for (int off = 1; off < 64; off <<= 1) m = fmaxf(m, __shfl_xor(m, off));
    float e[8]; float ssum = 0.f;
#pragma unroll
    for (int p = 0; p < 8; p++) {
        bool kp = val[p] && (key[p] >= Tkey);
        e[p] = kp ? expf(v[p] - m) : 0.f;
        ssum += e[p];
    }
#pragma unroll
    for (int off = 1; off < 64; off <<= 1) ssum += __shfl_xor(ssum, off);
    float inv = 1.f / ssum;
    bf16* sb = (bf16*)s;                  // in-place bf16 probs, row stride 1024 bf16
#pragma unroll
    for (int p = 0; p < 8; p++) sb[lane + 64 * p] = __float2bfloat16(e[p] * inv);
}

extern "C" void kernel_launch(void* const* d_in, const int* in_sizes, int n_in,
                              void* d_out, int out_size, void* d_ws, size_t ws_size,
                              hipStream_t stream)
{
    const float* x         = (const float*)d_in[0];
    const float* tf        = (const float*)d_in[1];
    const float* in_w      = (const float*)d_in[2];
    const float* in_b      = (const float*)d_in[3];
    const float* pos_emb   = (const float*)d_in[4];
    const float* temp_w    = (const float*)d_in[5];
    const float* temp_b    = (const float*)d_in[6];
    const float* pos_scale = (const float*)d_in[7];
    const float* temp_scale= (const float*)d_in[8];
    const float* conv_w    = (const float*)d_in[9];
    const float* conv_b    = (const float*)d_in[10];
    const float* qw        = (const float*)d_in[11];
    const float* qb        = (const float*)d_in[12];
    const float* kw        = (const float*)d_in[13];
    const float* kb        = (const float*)d_in[14];
    const float* vw        = (const float*)d_in[15];
    const float* vb        = (const float*)d_in[16];
    const float* ow        = (const float*)d_in[17];
    const float* ob        = (const float*)d_in[18];
    const float* f1w       = (const float*)d_in[19];
    const float* f1b       = (const float*)d_in[20];
    const float* f2w       = (const float*)d_in[21];
    const float* f2b       = (const float*)d_in[22];
    const float* n1s       = (const float*)d_in[23];
    const float* n1b       = (const float*)d_in[24];
    const float* n2s       = (const float*)d_in[25];
    const float* n2b       = (const float*)d_in[26];

    if (ws_size < (size_t)B_END) return;

    char* wsb = (char*)d_ws;
    float* h    = (float*)(wsb + B_H);
    float* tmp  = (float*)(wsb + B_TMP);
    float* scb  = (float*)(wsb + B_SC);
    float* extras = (float*)(wsb + B_SC);          // reuses scores region before attention
    bf16*  xb   = (bf16*)(wsb + B_HB);
    bf16*  inwT = (bf16*)(wsb + B_HB + 1048576);
    bf16*  hbp  = (bf16*)(wsb + B_HPAD);           // [8][514][512] padded bf16 h
    bf16*  qkv  = (bf16*)(wsb + B_QKV);
    bf16*  vT   = (bf16*)(wsb + B_VT);
    bf16*  ao   = (bf16*)(wsb + B_AO);
    bf16*  mid  = (bf16*)(wsb + B_MID);
    bf16*  wC   = (bf16*)(wsb + B_WC);
    bf16*  wQKV = (bf16*)(wsb + B_WQKV);
    bf16*  wO   = (bf16*)(wsb + B_WO);
    bf16*  wF1  = (bf16*)(wsb + B_WF1);
    bf16*  wF2  = (bf16*)(wsb + B_WF2);
    float* bqkv = (float*)(wsb + B_BIAS);

    // ---- weight prep ----
    convw_bf<<<(4 * 512 * 1536) / 256, 256, 0, stream>>>(conv_w, wC);
    {
        dim3 gw(16, 2, 1);
        wtrans<<<gw, 256, 0, stream>>>(in_w, inwT,         512, 64, 0L, 0L);
        dim3 g(16, 16, 4);
        wtrans<<<g, 256, 0, stream>>>(qw, wQKV,            512, 512, 262144L, 786432L);
        wtrans<<<g, 256, 0, stream>>>(kw, wQKV + 262144,   512, 512, 262144L, 786432L);
        wtrans<<<g, 256, 0, stream>>>(vw, wQKV + 524288,   512, 512, 262144L, 786432L);
        wtrans<<<g, 256, 0, stream>>>(ow, wO,              512, 512, 262144L, 262144L);
        dim3 g1(64, 16, 4);
        wtrans<<<g1, 256, 0, stream>>>(f1w, wF1,          2048, 512, 1048576L, 1048576L);
        dim3 g2(16, 64, 4);
        wtrans<<<g2, 256, 0, stream>>>(f2w, wF2,           512, 2048, 1048576L, 1048576L);
    }
    biascat<<<24, 256, 0, stream>>>(qb, kb, vb, bqkv);
    zpad<<<32, 256, 0, stream>>>(hbp);
    prep_embed<<<4096, 256, 0, stream>>>(x, tf, in_b, pos_emb, temp_w, temp_b,
                                         pos_scale, temp_scale, xb, extras);
    // embed = x @ in_w + extras  -> h (f32) + hbp (bf16, padded)
    {
        dim3 g(8, 128, 1);
        mm_bt<32><<<g, 64, 0, stream>>>(xb, 64, 0L, 0L,
                                        inwT, 64, 0L, 0L,
                                        h, nullptr, 512, 0L, 0L,
                                        64, 1, 512, 0,
                                        nullptr, extras, hbp, 0, 1.f);
    }

    for (int l = 0; l < El; l++) {
        // causal conv as GEMM over padded hbp window, K = 3*512, z-batched
        {
            dim3 g(8, 16, 8);
            mm_bt<32><<<g, 64, 0, stream>>>(hbp, 512, 263168L, 0L,
                                            wC + (long)l * 786432, 1536, 0L, 0L,
                                            tmp, nullptr, 512, 262144L, 0L,
                                            1536, 1, 512, 0,
                                            conv_b + (long)l * 512, nullptr, nullptr, 0, 1.f);
        }
        ln_kernel<<<Bsz * Lq, 256, 0, stream>>>(h, hbp, tmp, n1s + (long)l * 512, n1b + (long)l * 512);

        // fused QKV (z-batched over batch): [512,512] @ [512,1536] per b
        {
            dim3 g(24, 16, 8);
            mm_bt<32><<<g, 64, 0, stream>>>(hbp + 1024, 512, 263168L, 0L,
                                            wQKV + (long)l * 786432, 512, 0L, 0L,
                                            nullptr, qkv, 1536, 786432L, 0L,
                                            512, 1, 1536, 0,
                                            bqkv + (long)l * 1536, nullptr, nullptr, 0, 1.f);
        }

        // scores = 0.125 * q @ k^T (lower-triangle tiles) -> f32 scb
        {
            dim3 g(8, 16, 64);
            mm_bt<32><<<g, 64, 0, stream>>>(qkv, 1536, 786432L, 64L,
                                            qkv + 512, 1536, 786432L, 64L,
                                            scb, nullptr, 512, 2097152L, 262144L,
                                            64, 8, 512, 1,
                                            nullptr, nullptr, nullptr, 0, 0.125f);
        }
        topk_softmax<<<Bsz * Hh * Lq / 4, 256, 0, stream>>>(scb);
        {
            dim3 gv(8, 64, 1);
            vtrans<<<gv, 256, 0, stream>>>(qkv, vT);
        }
        // attn @ v : causal K limit, Nvalid=64
        {
            dim3 g(1, 32, 64);
            mm_bt<16><<<g, 64, 0, stream>>>((const bf16*)scb, 1024, 4194304L, 524288L,
                                            vT, 512, 262144L, 32768L,
                                            nullptr, ao, 512, 262144L, 64L,
                                            512, 8, 64, 2,
                                            nullptr, nullptr, nullptr, 0, 1.f);
        }
        // out proj
        {
            dim3 g(8, 128, 1);
            mm_bt<32><<<g, 64, 0, stream>>>(ao, 512, 0L, 0L,
                                            wO + (long)l * 262144, 512, 0L, 0L,
                                            tmp, nullptr, 512, 0L, 0L,
                                            512, 1, 512, 0,
                                            ob + (long)l * 512, nullptr, nullptr, 0, 1.f);
        }
        ln_kernel<<<Bsz * Lq, 256, 0, stream>>>(h, hbp, tmp, n2s + (long)l * 512, n2b + (long)l * 512);

        // FFN1 (relu) -> bf16 mid, z-batched
        {
            dim3 g(32, 16, 8);
            mm_bt<32><<<g, 64, 0, stream>>>(hbp + 1024, 512, 263168L, 0L,
                                            wF1 + (long)l * 1048576, 512, 0L, 0L,
                                            nullptr, mid, 2048, 1048576L, 0L,
                                            512, 1, 2048, 0,
                                            f1b + (long)l * 2048, nullptr, nullptr, 1, 1.f);
        }
        // FFN2 + residual -> f32 h + bf16 hbp (padded)
        {
            dim3 g(8, 128, 1);
            mm_bt<32><<<g, 64, 0, stream>>>(mid, 2048, 0L, 0L,
                                            wF2 + (long)l * 1048576, 2048, 0L, 0L,
                                            h, nullptr, 512, 0L, 0L,
                                            2048, 1, 512, 0,
                                            f2b + (long)l * 512, h, hbp, 0, 1.f);
        }
    }

    hipMemcpyAsync(d_out, h, (size_t)out_size * sizeof(float), hipMemcpyDeviceToDevice, stream);
}